// Round 2
// baseline (299.461 us; speedup 1.0000x reference)
//
#include <hip/hip_runtime.h>
#include <hip/hip_bf16.h>

#define Bn 8
#define Nn 4096
#define Cn 1024
#define Dn 512
#define Mn 64

typedef __hip_bfloat16 bf16;
typedef __attribute__((ext_vector_type(8))) short short8;
typedef __attribute__((ext_vector_type(4))) float f32x4;

#define MFMA16(a, b, c) __builtin_amdgcn_mfma_f32_16x16x32_bf16((a), (b), (c), 0, 0, 0)

__device__ inline short bfbits(float f) {
  union { bf16 b; short s; } u;
  u.b = __float2bfloat16(f);
  return u.s;
}

// ---------------------------------------------------------------------------
// K0: V[m][c] = sum_d av[m][d] * W[d][c]  (stored as bf16 hi + lo pair)
//     c0[m]  = sum_d av[m][d] * bias[d]
// grid (Mn, Cn/256), block 256.  All inputs fp32.
// ---------------------------------------------------------------------------
__global__ __launch_bounds__(256) void prep_kernel(
    const float* __restrict__ W, const float* __restrict__ bias,
    const float* __restrict__ av, bf16* __restrict__ Vhi,
    bf16* __restrict__ Vlo, float* __restrict__ c0) {
  const int m = blockIdx.x;
  const int c = blockIdx.y * 256 + threadIdx.x;
  float acc = 0.f;
  for (int d = 0; d < Dn; ++d) {
    acc = fmaf(av[m * Dn + d], W[d * Cn + c], acc);
  }
  const bf16 hi = __float2bfloat16(acc);
  Vhi[m * Cn + c] = hi;
  Vlo[m * Cn + c] = __float2bfloat16(acc - __bfloat162float(hi));

  if (blockIdx.y == 0) {  // block-uniform branch: one block per m does c0
    __shared__ float red[256];
    const int t = threadIdx.x;
    red[t] = av[m * Dn + t] * bias[t] + av[m * Dn + t + 256] * bias[t + 256];
    __syncthreads();
    for (int off = 128; off > 0; off >>= 1) {
      if (t < off) red[t] += red[t + off];
      __syncthreads();
    }
    if (t == 0) c0[m] = red[0];
  }
}

// ---------------------------------------------------------------------------
// K1: logits[b][m][n] = x[b][n][:] . V[m][:] + c0[m]   (fp32, layout B,M,N)
// block = 256 thr (4 waves), tile 64n x 64m, K-chunks of 64.
// x is fp32 in HBM -> converted to bf16 during LDS staging.
// Bhi = Vhi (LDS), Blo = Vlo (global, L2-resident) to split pipe load.
// grid (Nn/64, Bn)
// ---------------------------------------------------------------------------
__global__ __launch_bounds__(256) void logits_kernel(
    const float* __restrict__ x, const bf16* __restrict__ Vhi,
    const bf16* __restrict__ Vlo, const float* __restrict__ c0,
    float* __restrict__ logits) {
  const int n0 = blockIdx.x * 64;
  const int b = blockIdx.y;
  const int t = threadIdx.x;
  __shared__ short Xs[64][72];  // pad 72: 2-way-only bank aliasing (free)
  __shared__ short Vs[64][72];
  const int w = t >> 6, lane = t & 63, lr = lane & 15, q = lane >> 4;
  f32x4 acc[4];
#pragma unroll
  for (int i = 0; i < 4; ++i) acc[i] = (f32x4){0.f, 0.f, 0.f, 0.f};

  const int r = t >> 2;           // staging row 0..63
  const int cseg = (t & 3) * 16;  // 0,16,32,48
  const float* xrow = x + (size_t)(b * Nn + n0 + r) * Cn;

  for (int kc = 0; kc < Cn; kc += 64) {
    {
      const float4 f0 = *(const float4*)(xrow + kc + cseg);
      const float4 f1 = *(const float4*)(xrow + kc + cseg + 4);
      const float4 f2 = *(const float4*)(xrow + kc + cseg + 8);
      const float4 f3 = *(const float4*)(xrow + kc + cseg + 12);
      short8 s0, s1;
      s0[0] = bfbits(f0.x); s0[1] = bfbits(f0.y); s0[2] = bfbits(f0.z); s0[3] = bfbits(f0.w);
      s0[4] = bfbits(f1.x); s0[5] = bfbits(f1.y); s0[6] = bfbits(f1.z); s0[7] = bfbits(f1.w);
      s1[0] = bfbits(f2.x); s1[1] = bfbits(f2.y); s1[2] = bfbits(f2.z); s1[3] = bfbits(f2.w);
      s1[4] = bfbits(f3.x); s1[5] = bfbits(f3.y); s1[6] = bfbits(f3.z); s1[7] = bfbits(f3.w);
      *(short8*)&Xs[r][cseg] = s0;
      *(short8*)&Xs[r][cseg + 8] = s1;
      *(float4*)&Vs[r][cseg]     = *(const float4*)(Vhi + r * Cn + kc + cseg);
      *(float4*)&Vs[r][cseg + 8] = *(const float4*)(Vhi + r * Cn + kc + cseg + 8);
    }
    __syncthreads();
#pragma unroll
    for (int kk = 0; kk < 64; kk += 32) {
      const short8 a = *(const short8*)&Xs[w * 16 + lr][kk + q * 8];
#pragma unroll
      for (int mt = 0; mt < 4; ++mt) {
        const short8 bh = *(const short8*)&Vs[mt * 16 + lr][kk + q * 8];
        acc[mt] = MFMA16(a, bh, acc[mt]);
        const short8 bl = *(const short8*)(Vlo + (size_t)(mt * 16 + lr) * Cn + kc + kk + q * 8);
        acc[mt] = MFMA16(a, bl, acc[mt]);
      }
    }
    __syncthreads();
  }
  // D layout: row(n) = q*4+reg, col(m) = lane&15  [m89-verified]
#pragma unroll
  for (int mt = 0; mt < 4; ++mt) {
    const int m = mt * 16 + lr;
    const float bb = c0[m];
    float4 o;
    o.x = acc[mt][0] + bb; o.y = acc[mt][1] + bb;
    o.z = acc[mt][2] + bb; o.w = acc[mt][3] + bb;
    *(float4*)&logits[(size_t)(b * Mn + m) * Nn + n0 + w * 16 + q * 4] = o;
  }
}

// ---------------------------------------------------------------------------
// K2: softmax over N per (b,m) row; write bf16 weights. grid Bn*Mn, block 256
// ---------------------------------------------------------------------------
__global__ __launch_bounds__(256) void softmax_kernel(
    const float* __restrict__ logits, bf16* __restrict__ wgt) {
  const int row = blockIdx.x;
  const int t = threadIdx.x;
  const float* L = logits + (size_t)row * Nn;
  float v[16];
  float mx = -3.4e38f;
#pragma unroll
  for (int i = 0; i < 16; ++i) {
    v[i] = L[t + 256 * i];
    mx = fmaxf(mx, v[i]);
  }
#pragma unroll
  for (int off = 32; off > 0; off >>= 1) mx = fmaxf(mx, __shfl_down(mx, off));
  __shared__ float sred[4];
  if ((t & 63) == 0) sred[t >> 6] = mx;
  __syncthreads();
  mx = fmaxf(fmaxf(sred[0], sred[1]), fmaxf(sred[2], sred[3]));
  float sum = 0.f;
#pragma unroll
  for (int i = 0; i < 16; ++i) {
    v[i] = __expf(v[i] - mx);
    sum += v[i];
  }
#pragma unroll
  for (int off = 32; off > 0; off >>= 1) sum += __shfl_down(sum, off);
  __syncthreads();
  if ((t & 63) == 0) sred[t >> 6] = sum;
  __syncthreads();
  const float inv = 1.f / (sred[0] + sred[1] + sred[2] + sred[3]);
#pragma unroll
  for (int i = 0; i < 16; ++i)
    wgt[(size_t)row * Nn + t + 256 * i] = __float2bfloat16(v[i] * inv);
}

// ---------------------------------------------------------------------------
// K3: part[ks][b][m][c] = sum_{k in half ks} wgt[b][m][k] * x[b][k][c]
// block tile 64m x 64c, k-split 2.  x chunk (64k x 64c, fp32) converted to
// bf16 and transposed into LDS [c][k+pad] so B-frags are contiguous b128
// reads.  A-frags (weights, bf16) direct from global (k-contiguous rows).
// grid (Cn/64, Bn, 2)
// ---------------------------------------------------------------------------
__global__ __launch_bounds__(256) void pool_kernel(
    const float* __restrict__ x, const bf16* __restrict__ wgt,
    float* __restrict__ part) {
  const int cbase = blockIdx.x * 64;
  const int b = blockIdx.y;
  const int ks = blockIdx.z;
  const int t = threadIdx.x;
  __shared__ short XT[64][72];  // [c][k], pad 72
  const int w = t >> 6, lane = t & 63, lr = lane & 15, q = lane >> 4;
  const int mh = (w & 1) * 32, ch = (w >> 1) * 32;
  f32x4 acc[2][2];
#pragma unroll
  for (int i = 0; i < 2; ++i)
#pragma unroll
    for (int j = 0; j < 2; ++j) acc[i][j] = (f32x4){0.f, 0.f, 0.f, 0.f};

  const int kr = t >> 2;        // 0..63 k-row within chunk
  const int cs = (t & 3) * 16;  // 0,16,32,48
  const float* xb = x + (size_t)b * Nn * Cn;
  const bf16* wrow0 = wgt + (size_t)(b * Mn + mh + lr) * Nn;
  const bf16* wrow1 = wgt + (size_t)(b * Mn + mh + 16 + lr) * Nn;

  for (int kc = 0; kc < Nn / 2; kc += 64) {
    const int kglob = ks * (Nn / 2) + kc;
    {
      const float* src = xb + (size_t)(kglob + kr) * Cn + cbase + cs;
      const float4 f0 = *(const float4*)(src);
      const float4 f1 = *(const float4*)(src + 4);
      const float4 f2 = *(const float4*)(src + 8);
      const float4 f3 = *(const float4*)(src + 12);
      XT[cs +  0][kr] = bfbits(f0.x); XT[cs +  1][kr] = bfbits(f0.y);
      XT[cs +  2][kr] = bfbits(f0.z); XT[cs +  3][kr] = bfbits(f0.w);
      XT[cs +  4][kr] = bfbits(f1.x); XT[cs +  5][kr] = bfbits(f1.y);
      XT[cs +  6][kr] = bfbits(f1.z); XT[cs +  7][kr] = bfbits(f1.w);
      XT[cs +  8][kr] = bfbits(f2.x); XT[cs +  9][kr] = bfbits(f2.y);
      XT[cs + 10][kr] = bfbits(f2.z); XT[cs + 11][kr] = bfbits(f2.w);
      XT[cs + 12][kr] = bfbits(f3.x); XT[cs + 13][kr] = bfbits(f3.y);
      XT[cs + 14][kr] = bfbits(f3.z); XT[cs + 15][kr] = bfbits(f3.w);
    }
    __syncthreads();
#pragma unroll
    for (int kk = 0; kk < 64; kk += 32) {
      const short8 a0 = *(const short8*)(wrow0 + kglob + kk + q * 8);
      const short8 a1 = *(const short8*)(wrow1 + kglob + kk + q * 8);
      const short8 b0 = *(const short8*)&XT[ch + lr][kk + q * 8];
      const short8 b1 = *(const short8*)&XT[ch + 16 + lr][kk + q * 8];
      acc[0][0] = MFMA16(a0, b0, acc[0][0]);
      acc[0][1] = MFMA16(a0, b1, acc[0][1]);
      acc[1][0] = MFMA16(a1, b0, acc[1][0]);
      acc[1][1] = MFMA16(a1, b1, acc[1][1]);
    }
    __syncthreads();
  }
  float* pout = part + (size_t)(ks * Bn + b) * Mn * Cn;
#pragma unroll
  for (int mi = 0; mi < 2; ++mi)
#pragma unroll
    for (int ci = 0; ci < 2; ++ci) {
      const int m = mh + mi * 16 + q * 4;
      const int c = cbase + ch + ci * 16 + lr;
#pragma unroll
      for (int reg = 0; reg < 4; ++reg)
        pout[(size_t)(m + reg) * Cn + c] = acc[mi][ci][reg];
    }
}

// ---------------------------------------------------------------------------
// K4: out = fp32(part[0] + part[1])   grid 2048, block 256
// ---------------------------------------------------------------------------
__global__ __launch_bounds__(256) void reduce_kernel(
    const float* __restrict__ part, float* __restrict__ out) {
  const int idx = blockIdx.x * 256 + threadIdx.x;
  out[idx] = part[idx] + part[idx + Bn * Mn * Cn];
}

extern "C" void kernel_launch(void* const* d_in, const int* in_sizes, int n_in,
                              void* d_out, int out_size, void* d_ws, size_t ws_size,
                              hipStream_t stream) {
  const float* x = (const float*)d_in[0];
  const float* W = (const float*)d_in[1];
  const float* bias = (const float*)d_in[2];
  const float* av = (const float*)d_in[3];
  float* out = (float*)d_out;
  char* ws = (char*)d_ws;

  bf16* Vhi = (bf16*)(ws + 0);            // 131072 B
  bf16* Vlo = (bf16*)(ws + 131072);       // 131072 B
  float* c0 = (float*)(ws + 262144);      // 256 B (padded to 1024)
  float* logits = (float*)(ws + 263168);  // 8388608 B
  bf16* wgt = (bf16*)(ws + 8651776);      // 4194304 B
  float* part = (float*)(ws + 12846080);  // 4194304 B  (total ~16.3 MB)

  prep_kernel<<<dim3(Mn, Cn / 256), 256, 0, stream>>>(W, bias, av, Vhi, Vlo, c0);
  logits_kernel<<<dim3(Nn / 64, Bn), 256, 0, stream>>>(x, Vhi, Vlo, c0, logits);
  softmax_kernel<<<Bn * Mn, 256, 0, stream>>>(logits, wgt);
  pool_kernel<<<dim3(Cn / 64, Bn, 2), 256, 0, stream>>>(x, wgt, part);
  reduce_kernel<<<(Bn * Mn * Cn) / 256, 256, 0, stream>>>(part, out);
}

// Round 3
// 286.770 us; speedup vs baseline: 1.0443x; 1.0443x over previous
//
#include <hip/hip_runtime.h>
#include <hip/hip_bf16.h>

#define Bn 8
#define Nn 4096
#define Cn 1024
#define Dn 512
#define Mn 64

typedef __hip_bfloat16 bf16;
typedef __attribute__((ext_vector_type(8))) short short8;
typedef __attribute__((ext_vector_type(4))) short short4x;
typedef __attribute__((ext_vector_type(4))) float f32x4;

#define MFMA16(a, b, c) __builtin_amdgcn_mfma_f32_16x16x32_bf16((a), (b), (c), 0, 0, 0)

__device__ inline short bfbits(float f) {
  union { bf16 b; short s; } u;
  u.b = __float2bfloat16(f);
  return u.s;
}

// ---------------------------------------------------------------------------
// K0: V[m][c] = sum_d av[m][d]*W[d][c]  (bf16 hi+lo);  c0[m] = av[m,:].bias
// grid (Mn, Cn/64) = 1024 blocks, block 256 = 64c x 4 d-groups (ILP + LDS red)
// ---------------------------------------------------------------------------
__global__ __launch_bounds__(256) void prep_kernel(
    const float* __restrict__ W, const float* __restrict__ bias,
    const float* __restrict__ av, bf16* __restrict__ Vhi,
    bf16* __restrict__ Vlo, float* __restrict__ c0) {
  const int m = blockIdx.x;
  const int t = threadIdx.x;
  const int cl = t & 63, dg = t >> 6;
  const int c = blockIdx.y * 64 + cl;
  const float* wp = W + (size_t)(dg * 128) * Cn + c;
  const float* ap = av + m * Dn + dg * 128;
  float a0 = 0.f, a1 = 0.f, a2 = 0.f, a3 = 0.f;
#pragma unroll 8
  for (int i = 0; i < 128; i += 4) {
    a0 = fmaf(ap[i + 0], wp[(size_t)(i + 0) * Cn], a0);
    a1 = fmaf(ap[i + 1], wp[(size_t)(i + 1) * Cn], a1);
    a2 = fmaf(ap[i + 2], wp[(size_t)(i + 2) * Cn], a2);
    a3 = fmaf(ap[i + 3], wp[(size_t)(i + 3) * Cn], a3);
  }
  __shared__ float red[256];
  red[t] = (a0 + a1) + (a2 + a3);
  __syncthreads();
  const float v = red[cl] + red[cl + 64] + red[cl + 128] + red[cl + 192];
  if (dg == 0) {
    const bf16 hi = __float2bfloat16(v);
    Vhi[m * Cn + c] = hi;
    Vlo[m * Cn + c] = __float2bfloat16(v - __bfloat162float(hi));
  }
  if (blockIdx.y == 0) {  // block-uniform
    __syncthreads();
    red[t] = av[m * Dn + t] * bias[t] + av[m * Dn + t + 256] * bias[t + 256];
    __syncthreads();
    if (t < 64) {
      float s = red[t] + red[t + 64] + red[t + 128] + red[t + 192];
#pragma unroll
      for (int off = 32; off > 0; off >>= 1) s += __shfl_down(s, off);
      if (t == 0) c0[m] = s;
    }
  }
}

// ---------------------------------------------------------------------------
// K1: logits[b][m][n] = x[b][n][:].V[m][:] + c0[m]
// NO LDS, NO barriers. wave = 16n x 64m, full K. A-frags: 2 float4 global
// loads + in-reg cvt (A[m=lr][k=q*8+j]).  B-frags (Vhi/Vlo): 16B global
// loads, L1/L2-resident.  x stream prefetched 1 iter ahead.
// grid (Nn/64, Bn) = 512 blocks, block 256 (4 waves)
// ---------------------------------------------------------------------------
__global__ __launch_bounds__(256) void logits_kernel(
    const float* __restrict__ x, const bf16* __restrict__ Vhi,
    const bf16* __restrict__ Vlo, const float* __restrict__ c0,
    float* __restrict__ logits) {
  const int n0 = blockIdx.x * 64;
  const int b = blockIdx.y;
  const int t = threadIdx.x;
  const int w = t >> 6, lane = t & 63, lr = lane & 15, q = lane >> 4;
  const float* xrow = x + (size_t)(b * Nn + n0 + w * 16 + lr) * Cn + q * 8;
  f32x4 acc[4];
#pragma unroll
  for (int i = 0; i < 4; ++i) acc[i] = (f32x4){0.f, 0.f, 0.f, 0.f};

  float4 f0 = *(const float4*)(xrow);
  float4 f1 = *(const float4*)(xrow + 4);
  for (int k0 = 0; k0 < Cn; k0 += 32) {
    const float4 c0v = f0, c1v = f1;
    if (k0 + 32 < Cn) {  // prefetch next x chunk
      f0 = *(const float4*)(xrow + k0 + 32);
      f1 = *(const float4*)(xrow + k0 + 36);
    }
    short8 a;
    a[0] = bfbits(c0v.x); a[1] = bfbits(c0v.y); a[2] = bfbits(c0v.z); a[3] = bfbits(c0v.w);
    a[4] = bfbits(c1v.x); a[5] = bfbits(c1v.y); a[6] = bfbits(c1v.z); a[7] = bfbits(c1v.w);
    const int ka = k0 + q * 8;
#pragma unroll
    for (int mt = 0; mt < 4; ++mt) {
      const short8 bh = *(const short8*)(Vhi + (size_t)(mt * 16 + lr) * Cn + ka);
      acc[mt] = MFMA16(a, bh, acc[mt]);
      const short8 bl = *(const short8*)(Vlo + (size_t)(mt * 16 + lr) * Cn + ka);
      acc[mt] = MFMA16(a, bl, acc[mt]);
    }
  }
  // D layout: row(n)=q*4+reg, col(m)=lr
#pragma unroll
  for (int mt = 0; mt < 4; ++mt) {
    const int m = mt * 16 + lr;
    const float bb = c0[m];
    float4 o;
    o.x = acc[mt][0] + bb; o.y = acc[mt][1] + bb;
    o.z = acc[mt][2] + bb; o.w = acc[mt][3] + bb;
    *(float4*)&logits[(size_t)(b * Mn + m) * Nn + n0 + w * 16 + q * 4] = o;
  }
}

// ---------------------------------------------------------------------------
// K2: softmax over N per (b,m) row; bf16 weights out. grid Bn*Mn, block 256
// ---------------------------------------------------------------------------
__global__ __launch_bounds__(256) void softmax_kernel(
    const float* __restrict__ logits, bf16* __restrict__ wgt) {
  const int row = blockIdx.x;
  const int t = threadIdx.x;
  const float* L = logits + (size_t)row * Nn;
  float v[16];
  float mx = -3.4e38f;
#pragma unroll
  for (int i = 0; i < 16; ++i) {
    v[i] = L[t + 256 * i];
    mx = fmaxf(mx, v[i]);
  }
#pragma unroll
  for (int off = 32; off > 0; off >>= 1) mx = fmaxf(mx, __shfl_down(mx, off));
  __shared__ float sred[4];
  if ((t & 63) == 0) sred[t >> 6] = mx;
  __syncthreads();
  mx = fmaxf(fmaxf(sred[0], sred[1]), fmaxf(sred[2], sred[3]));
  float sum = 0.f;
#pragma unroll
  for (int i = 0; i < 16; ++i) {
    v[i] = __expf(v[i] - mx);
    sum += v[i];
  }
#pragma unroll
  for (int off = 32; off > 0; off >>= 1) sum += __shfl_down(sum, off);
  __syncthreads();
  if ((t & 63) == 0) sred[t >> 6] = sum;
  __syncthreads();
  const float inv = 1.f / (sred[0] + sred[1] + sred[2] + sred[3]);
#pragma unroll
  for (int i = 0; i < 16; ++i)
    wgt[(size_t)row * Nn + t + 256 * i] = __float2bfloat16(v[i] * inv);
}

// ---------------------------------------------------------------------------
// K3: part[ks][b][m][c] = sum_{k in quarter ks} wgt[b][m][k]*x[b][k][c]
// k-split 4 (2 blocks/CU).  Staging: 4x4 register transpose, 4 ds_write_b64
// per thread.  XT stride 72 shorts (144B: 16B-mult for b128 reads).
// grid (Cn/64, Bn, 4), block 256
// ---------------------------------------------------------------------------
__global__ __launch_bounds__(256) void pool_kernel(
    const float* __restrict__ x, const bf16* __restrict__ wgt,
    float* __restrict__ part) {
  const int cbase = blockIdx.x * 64;
  const int b = blockIdx.y;
  const int ks = blockIdx.z;
  const int t = threadIdx.x;
  __shared__ short XT[64][72];  // [c][k]
  const int w = t >> 6, lane = t & 63, lr = lane & 15, q = lane >> 4;
  const int mh = (w & 1) * 32, ch = (w >> 1) * 32;
  f32x4 acc[2][2];
#pragma unroll
  for (int i = 0; i < 2; ++i)
#pragma unroll
    for (int j = 0; j < 2; ++j) acc[i][j] = (f32x4){0.f, 0.f, 0.f, 0.f};

  const int g = t & 15;   // k-group: rows 4g..4g+3
  const int h = t >> 4;   // c-group: cols 4h..4h+3
  const float* xb = x + (size_t)b * Nn * Cn;
  const bf16* wrow0 = wgt + (size_t)(b * Mn + mh + lr) * Nn;
  const bf16* wrow1 = wgt + (size_t)(b * Mn + mh + 16 + lr) * Nn;

  for (int kc = 0; kc < Nn / 4; kc += 64) {
    const int kglob = ks * (Nn / 4) + kc;
    {
      const float* src = xb + (size_t)(kglob + 4 * g) * Cn + cbase + 4 * h;
      const float4 r0 = *(const float4*)(src);
      const float4 r1 = *(const float4*)(src + Cn);
      const float4 r2 = *(const float4*)(src + 2 * Cn);
      const float4 r3 = *(const float4*)(src + 3 * Cn);
      short4x w0, w1, w2, w3;
      w0[0] = bfbits(r0.x); w0[1] = bfbits(r1.x); w0[2] = bfbits(r2.x); w0[3] = bfbits(r3.x);
      w1[0] = bfbits(r0.y); w1[1] = bfbits(r1.y); w1[2] = bfbits(r2.y); w1[3] = bfbits(r3.y);
      w2[0] = bfbits(r0.z); w2[1] = bfbits(r1.z); w2[2] = bfbits(r2.z); w2[3] = bfbits(r3.z);
      w3[0] = bfbits(r0.w); w3[1] = bfbits(r1.w); w3[2] = bfbits(r2.w); w3[3] = bfbits(r3.w);
      *(short4x*)&XT[4 * h + 0][4 * g] = w0;
      *(short4x*)&XT[4 * h + 1][4 * g] = w1;
      *(short4x*)&XT[4 * h + 2][4 * g] = w2;
      *(short4x*)&XT[4 * h + 3][4 * g] = w3;
    }
    __syncthreads();
#pragma unroll
    for (int kk = 0; kk < 64; kk += 32) {
      const short8 a0 = *(const short8*)(wrow0 + kglob + kk + q * 8);
      const short8 a1 = *(const short8*)(wrow1 + kglob + kk + q * 8);
      const short8 b0 = *(const short8*)&XT[ch + lr][kk + q * 8];
      const short8 b1 = *(const short8*)&XT[ch + 16 + lr][kk + q * 8];
      acc[0][0] = MFMA16(a0, b0, acc[0][0]);
      acc[0][1] = MFMA16(a0, b1, acc[0][1]);
      acc[1][0] = MFMA16(a1, b0, acc[1][0]);
      acc[1][1] = MFMA16(a1, b1, acc[1][1]);
    }
    __syncthreads();
  }
  float* pout = part + ((size_t)ks * Bn + b) * Mn * Cn;
#pragma unroll
  for (int mi = 0; mi < 2; ++mi)
#pragma unroll
    for (int ci = 0; ci < 2; ++ci) {
      const int m = mh + mi * 16 + q * 4;
      const int c = cbase + ch + ci * 16 + lr;
#pragma unroll
      for (int reg = 0; reg < 4; ++reg)
        pout[(size_t)(m + reg) * Cn + c] = acc[mi][ci][reg];
    }
}

// ---------------------------------------------------------------------------
// K4: out = sum of 4 partials (float4).  grid 512, block 256
// ---------------------------------------------------------------------------
__global__ __launch_bounds__(256) void reduce_kernel(
    const float* __restrict__ part, float* __restrict__ out) {
  const int i = blockIdx.x * 256 + threadIdx.x;
  const float4* p = (const float4*)part;
  const int S4 = (Bn * Mn * Cn) / 4;
  const float4 v0 = p[i], v1 = p[i + S4], v2 = p[i + 2 * S4], v3 = p[i + 3 * S4];
  float4 o;
  o.x = (v0.x + v1.x) + (v2.x + v3.x);
  o.y = (v0.y + v1.y) + (v2.y + v3.y);
  o.z = (v0.z + v1.z) + (v2.z + v3.z);
  o.w = (v0.w + v1.w) + (v2.w + v3.w);
  ((float4*)out)[i] = o;
}

extern "C" void kernel_launch(void* const* d_in, const int* in_sizes, int n_in,
                              void* d_out, int out_size, void* d_ws, size_t ws_size,
                              hipStream_t stream) {
  const float* x = (const float*)d_in[0];
  const float* W = (const float*)d_in[1];
  const float* bias = (const float*)d_in[2];
  const float* av = (const float*)d_in[3];
  float* out = (float*)d_out;
  char* ws = (char*)d_ws;

  bf16* Vhi = (bf16*)(ws + 0);            // 131072 B
  bf16* Vlo = (bf16*)(ws + 131072);       // 131072 B
  float* c0 = (float*)(ws + 262144);      // 1024 B
  float* logits = (float*)(ws + 263168);  // 8388608 B
  bf16* wgt = (bf16*)(ws + 8651776);      // 4194304 B
  float* part = (float*)(ws + 12846080);  // 4 x 2097152 B  (total ~20.3 MB)

  prep_kernel<<<dim3(Mn, Cn / 64), 256, 0, stream>>>(W, bias, av, Vhi, Vlo, c0);
  logits_kernel<<<dim3(Nn / 64, Bn), 256, 0, stream>>>(x, Vhi, Vlo, c0, logits);
  softmax_kernel<<<Bn * Mn, 256, 0, stream>>>(logits, wgt);
  pool_kernel<<<dim3(Cn / 64, Bn, 4), 256, 0, stream>>>(x, wgt, part);
  reduce_kernel<<<(Bn * Mn * Cn) / 1024, 256, 0, stream>>>(part, out);
}

// Round 4
// 244.911 us; speedup vs baseline: 1.2227x; 1.1709x over previous
//
#include <hip/hip_runtime.h>
#include <hip/hip_bf16.h>

#define Bn 8
#define Nn 4096
#define Cn 1024
#define Dn 512
#define Mn 64

typedef __hip_bfloat16 bf16;
typedef __attribute__((ext_vector_type(8))) short short8;
typedef __attribute__((ext_vector_type(4))) short short4x;
typedef __attribute__((ext_vector_type(4))) float f32x4;

#define MFMA16(a, b, c) __builtin_amdgcn_mfma_f32_16x16x32_bf16((a), (b), (c), 0, 0, 0)

__device__ inline short bfbits(float f) {
  union { bf16 b; short s; } u;
  u.b = __float2bfloat16(f);
  return u.s;
}

// ---------------------------------------------------------------------------
// K0: V[m][c] = sum_d av[m][d]*W[d][c]  (bf16 hi+lo);  c0[m] = av[m,:].bias
// grid (Mn, Cn/64) = 1024 blocks, block 256 = 64c x 4 d-groups (ILP + LDS red)
// ---------------------------------------------------------------------------
__global__ __launch_bounds__(256) void prep_kernel(
    const float* __restrict__ W, const float* __restrict__ bias,
    const float* __restrict__ av, bf16* __restrict__ Vhi,
    bf16* __restrict__ Vlo, float* __restrict__ c0) {
  const int m = blockIdx.x;
  const int t = threadIdx.x;
  const int cl = t & 63, dg = t >> 6;
  const int c = blockIdx.y * 64 + cl;
  const float* wp = W + (size_t)(dg * 128) * Cn + c;
  const float* ap = av + m * Dn + dg * 128;
  float a0 = 0.f, a1 = 0.f, a2 = 0.f, a3 = 0.f;
#pragma unroll 8
  for (int i = 0; i < 128; i += 4) {
    a0 = fmaf(ap[i + 0], wp[(size_t)(i + 0) * Cn], a0);
    a1 = fmaf(ap[i + 1], wp[(size_t)(i + 1) * Cn], a1);
    a2 = fmaf(ap[i + 2], wp[(size_t)(i + 2) * Cn], a2);
    a3 = fmaf(ap[i + 3], wp[(size_t)(i + 3) * Cn], a3);
  }
  __shared__ float red[256];
  red[t] = (a0 + a1) + (a2 + a3);
  __syncthreads();
  const float v = red[cl] + red[cl + 64] + red[cl + 128] + red[cl + 192];
  if (dg == 0) {
    const bf16 hi = __float2bfloat16(v);
    Vhi[m * Cn + c] = hi;
    Vlo[m * Cn + c] = __float2bfloat16(v - __bfloat162float(hi));
  }
  if (blockIdx.y == 0) {  // block-uniform
    __syncthreads();
    red[t] = av[m * Dn + t] * bias[t] + av[m * Dn + t + 256] * bias[t + 256];
    __syncthreads();
    if (t < 64) {
      float s = red[t] + red[t + 64] + red[t + 128] + red[t + 192];
#pragma unroll
      for (int off = 32; off > 0; off >>= 1) s += __shfl_down(s, off);
      if (t == 0) c0[m] = s;
    }
  }
}

// ---------------------------------------------------------------------------
// K1: logits[b][m][n] = x[b][n][:].V[m][:] + c0[m]
// Tile 64n x 64m, K-chunks of 128.  x (fp32->bf16), Vhi, Vlo all staged in
// LDS with fully-coalesced loads (16 adjacent lanes -> 512B contiguous) and
// 1-chunk-ahead register prefetch.  Stride 136 shorts: 2-way banks (free).
// grid (Nn/64, Bn) = 512, block 256 (4 waves); LDS 52KB -> 3 blocks/CU.
// ---------------------------------------------------------------------------
__global__ __launch_bounds__(256) void logits_kernel(
    const float* __restrict__ x, const bf16* __restrict__ Vhi,
    const bf16* __restrict__ Vlo, const float* __restrict__ c0,
    float* __restrict__ logits) {
  const int n0 = blockIdx.x * 64;
  const int b = blockIdx.y;
  const int t = threadIdx.x;
  __shared__ short Xs[64][136];
  __shared__ short VsH[64][136];
  __shared__ short VsL[64][136];
  const int w = t >> 6, lane = t & 63, lr = lane & 15, q = lane >> 4;
  const ptrdiff_t dlo = Vlo - Vhi;

  // staging unit u = t + 256j: row = u>>4, col-16B-unit = u&15
  int ur[4], uc[4];
  const float* xsrc[4];
  const bf16* hsrc[4];
#pragma unroll
  for (int j = 0; j < 4; ++j) {
    const int u = t + 256 * j;
    ur[j] = u >> 4;
    uc[j] = (u & 15) * 8;
    xsrc[j] = x + (size_t)(b * Nn + n0 + ur[j]) * Cn + uc[j];
    hsrc[j] = Vhi + ur[j] * Cn + uc[j];
  }

  f32x4 acc[4];
#pragma unroll
  for (int i = 0; i < 4; ++i) acc[i] = (f32x4){0.f, 0.f, 0.f, 0.f};

  float4 px0[4], px1[4];
  short8 pvh[4], pvl[4];
#pragma unroll
  for (int j = 0; j < 4; ++j) {  // prologue prefetch: chunk 0
    px0[j] = *(const float4*)(xsrc[j]);
    px1[j] = *(const float4*)(xsrc[j] + 4);
    pvh[j] = *(const short8*)(hsrc[j]);
    pvl[j] = *(const short8*)(hsrc[j] + dlo);
  }

  for (int k0 = 0; k0 < Cn; k0 += 128) {
#pragma unroll
    for (int j = 0; j < 4; ++j) {
      short8 s;
      s[0] = bfbits(px0[j].x); s[1] = bfbits(px0[j].y);
      s[2] = bfbits(px0[j].z); s[3] = bfbits(px0[j].w);
      s[4] = bfbits(px1[j].x); s[5] = bfbits(px1[j].y);
      s[6] = bfbits(px1[j].z); s[7] = bfbits(px1[j].w);
      *(short8*)&Xs[ur[j]][uc[j]] = s;
      *(short8*)&VsH[ur[j]][uc[j]] = pvh[j];
      *(short8*)&VsL[ur[j]][uc[j]] = pvl[j];
    }
    __syncthreads();
    if (k0 + 128 < Cn) {  // prefetch next chunk while computing this one
#pragma unroll
      for (int j = 0; j < 4; ++j) {
        px0[j] = *(const float4*)(xsrc[j] + k0 + 128);
        px1[j] = *(const float4*)(xsrc[j] + k0 + 132);
        pvh[j] = *(const short8*)(hsrc[j] + k0 + 128);
        pvl[j] = *(const short8*)(hsrc[j] + dlo + k0 + 128);
      }
    }
#pragma unroll
    for (int kk = 0; kk < 128; kk += 32) {
      const short8 a = *(const short8*)&Xs[w * 16 + lr][kk + q * 8];
#pragma unroll
      for (int mt = 0; mt < 4; ++mt) {
        acc[mt] = MFMA16(a, *(const short8*)&VsH[mt * 16 + lr][kk + q * 8], acc[mt]);
        acc[mt] = MFMA16(a, *(const short8*)&VsL[mt * 16 + lr][kk + q * 8], acc[mt]);
      }
    }
    __syncthreads();
  }
  // D layout: row(n)=q*4+reg, col(m)=lr  [m89-verified]
#pragma unroll
  for (int mt = 0; mt < 4; ++mt) {
    const int m = mt * 16 + lr;
    const float bb = c0[m];
    float4 o;
    o.x = acc[mt][0] + bb; o.y = acc[mt][1] + bb;
    o.z = acc[mt][2] + bb; o.w = acc[mt][3] + bb;
    *(float4*)&logits[(size_t)(b * Mn + m) * Nn + n0 + w * 16 + q * 4] = o;
  }
}

// ---------------------------------------------------------------------------
// K2: softmax over N per (b,m) row; bf16 weights out. grid Bn*Mn, block 256
// ---------------------------------------------------------------------------
__global__ __launch_bounds__(256) void softmax_kernel(
    const float* __restrict__ logits, bf16* __restrict__ wgt) {
  const int row = blockIdx.x;
  const int t = threadIdx.x;
  const float* L = logits + (size_t)row * Nn;
  float v[16];
  float mx = -3.4e38f;
#pragma unroll
  for (int i = 0; i < 16; ++i) {
    v[i] = L[t + 256 * i];
    mx = fmaxf(mx, v[i]);
  }
#pragma unroll
  for (int off = 32; off > 0; off >>= 1) mx = fmaxf(mx, __shfl_down(mx, off));
  __shared__ float sred[4];
  if ((t & 63) == 0) sred[t >> 6] = mx;
  __syncthreads();
  mx = fmaxf(fmaxf(sred[0], sred[1]), fmaxf(sred[2], sred[3]));
  float sum = 0.f;
#pragma unroll
  for (int i = 0; i < 16; ++i) {
    v[i] = __expf(v[i] - mx);
    sum += v[i];
  }
#pragma unroll
  for (int off = 32; off > 0; off >>= 1) sum += __shfl_down(sum, off);
  __syncthreads();
  if ((t & 63) == 0) sred[t >> 6] = sum;
  __syncthreads();
  const float inv = 1.f / (sred[0] + sred[1] + sred[2] + sred[3]);
#pragma unroll
  for (int i = 0; i < 16; ++i)
    wgt[(size_t)row * Nn + t + 256 * i] = __float2bfloat16(v[i] * inv);
}

// ---------------------------------------------------------------------------
// K3: part[ks][b][m][c] = sum_{k-quarter} wgt[b][m][k]*x[b][k][c]
// K-chunks of 128.  Coalesced staging: thread (h=t&15,g=t>>4) loads rows
// {4g+i, 64+4g+i} cols [4h,4h+4) -> 16 lanes give 256B contiguous segments.
// 4x4 register transpose -> b64 writes into XT[c][k^swz], swz=8*((c>>2)&7)
// (write pos == read pos since swz only touches bits>=3; b128 reads
// conflict-free).  x prefetched 1 chunk ahead.  wgt A-frags direct from
// global (k-contiguous, L2-resident).  grid (Cn/64, Bn, 4) = 512, block 256.
// ---------------------------------------------------------------------------
__global__ __launch_bounds__(256) void pool_kernel(
    const float* __restrict__ x, const bf16* __restrict__ wgt,
    float* __restrict__ part) {
  const int cbase = blockIdx.x * 64;
  const int b = blockIdx.y;
  const int ks = blockIdx.z;
  const int t = threadIdx.x;
  __shared__ short XT[64][136];  // [c][k-swizzled]
  const int w = t >> 6, lane = t & 63, lr = lane & 15, q = lane >> 4;
  const int mh = (w & 1) * 32, ch = (w >> 1) * 32;
  f32x4 acc[2][2];
#pragma unroll
  for (int i = 0; i < 2; ++i)
#pragma unroll
    for (int j = 0; j < 2; ++j) acc[i][j] = (f32x4){0.f, 0.f, 0.f, 0.f};

  const int h = t & 15, g = t >> 4;
  const int swz = 8 * (h & 7);  // this thread's cols are 4h..4h+3 -> c>>2 == h
  const int swzr0 = 8 * (((ch + lr) >> 2) & 7);
  const int swzr1 = 8 * (((ch + 16 + lr) >> 2) & 7);
  const int kbase = ks * (Nn / 4);
  const float* xsrc = x + (size_t)b * Nn * Cn + (size_t)(kbase + 4 * g) * Cn + cbase + 4 * h;
  const bf16* wr0 = wgt + (size_t)(b * Mn + mh + lr) * Nn + kbase;
  const bf16* wr1 = wr0 + (size_t)16 * Nn;

  float4 pf[8];
#pragma unroll
  for (int i = 0; i < 4; ++i) {  // prologue prefetch: chunk 0
    pf[i]     = *(const float4*)(xsrc + (size_t)i * Cn);
    pf[4 + i] = *(const float4*)(xsrc + (size_t)(64 + i) * Cn);
  }

  for (int kc = 0; kc < Nn / 4; kc += 128) {
#pragma unroll
    for (int blk = 0; blk < 2; ++blk) {
      const float4 r0 = pf[blk * 4 + 0], r1 = pf[blk * 4 + 1];
      const float4 r2 = pf[blk * 4 + 2], r3 = pf[blk * 4 + 3];
      const int kof = (blk * 64 + 4 * g) ^ swz;
      short4x v0, v1, v2, v3;
      v0[0] = bfbits(r0.x); v0[1] = bfbits(r1.x); v0[2] = bfbits(r2.x); v0[3] = bfbits(r3.x);
      v1[0] = bfbits(r0.y); v1[1] = bfbits(r1.y); v1[2] = bfbits(r2.y); v1[3] = bfbits(r3.y);
      v2[0] = bfbits(r0.z); v2[1] = bfbits(r1.z); v2[2] = bfbits(r2.z); v2[3] = bfbits(r3.z);
      v3[0] = bfbits(r0.w); v3[1] = bfbits(r1.w); v3[2] = bfbits(r2.w); v3[3] = bfbits(r3.w);
      *(short4x*)&XT[4 * h + 0][kof] = v0;
      *(short4x*)&XT[4 * h + 1][kof] = v1;
      *(short4x*)&XT[4 * h + 2][kof] = v2;
      *(short4x*)&XT[4 * h + 3][kof] = v3;
    }
    __syncthreads();
    if (kc + 128 < Nn / 4) {  // prefetch next chunk
#pragma unroll
      for (int i = 0; i < 4; ++i) {
        pf[i]     = *(const float4*)(xsrc + (size_t)(kc + 128 + i) * Cn);
        pf[4 + i] = *(const float4*)(xsrc + (size_t)(kc + 192 + i) * Cn);
      }
    }
#pragma unroll
    for (int kk = 0; kk < 128; kk += 32) {
      const short8 a0 = *(const short8*)(wr0 + kc + kk + q * 8);
      const short8 a1 = *(const short8*)(wr1 + kc + kk + q * 8);
      const short8 b0 = *(const short8*)&XT[ch + lr][(kk + q * 8) ^ swzr0];
      const short8 b1 = *(const short8*)&XT[ch + 16 + lr][(kk + q * 8) ^ swzr1];
      acc[0][0] = MFMA16(a0, b0, acc[0][0]);
      acc[0][1] = MFMA16(a0, b1, acc[0][1]);
      acc[1][0] = MFMA16(a1, b0, acc[1][0]);
      acc[1][1] = MFMA16(a1, b1, acc[1][1]);
    }
    __syncthreads();
  }
  float* pout = part + ((size_t)ks * Bn + b) * Mn * Cn;
#pragma unroll
  for (int mi = 0; mi < 2; ++mi)
#pragma unroll
    for (int ci = 0; ci < 2; ++ci) {
      const int m = mh + mi * 16 + q * 4;
      const int c = cbase + ch + ci * 16 + lr;
#pragma unroll
      for (int reg = 0; reg < 4; ++reg)
        pout[(size_t)(m + reg) * Cn + c] = acc[mi][ci][reg];
    }
}

// ---------------------------------------------------------------------------
// K4: out = sum of 4 partials (float4).  grid 512, block 256
// ---------------------------------------------------------------------------
__global__ __launch_bounds__(256) void reduce_kernel(
    const float* __restrict__ part, float* __restrict__ out) {
  const int i = blockIdx.x * 256 + threadIdx.x;
  const float4* p = (const float4*)part;
  const int S4 = (Bn * Mn * Cn) / 4;
  const float4 v0 = p[i], v1 = p[i + S4], v2 = p[i + 2 * S4], v3 = p[i + 3 * S4];
  float4 o;
  o.x = (v0.x + v1.x) + (v2.x + v3.x);
  o.y = (v0.y + v1.y) + (v2.y + v3.y);
  o.z = (v0.z + v1.z) + (v2.z + v3.z);
  o.w = (v0.w + v1.w) + (v2.w + v3.w);
  ((float4*)out)[i] = o;
}

extern "C" void kernel_launch(void* const* d_in, const int* in_sizes, int n_in,
                              void* d_out, int out_size, void* d_ws, size_t ws_size,
                              hipStream_t stream) {
  const float* x = (const float*)d_in[0];
  const float* W = (const float*)d_in[1];
  const float* bias = (const float*)d_in[2];
  const float* av = (const float*)d_in[3];
  float* out = (float*)d_out;
  char* ws = (char*)d_ws;

  bf16* Vhi = (bf16*)(ws + 0);            // 131072 B
  bf16* Vlo = (bf16*)(ws + 131072);       // 131072 B
  float* c0 = (float*)(ws + 262144);      // 1024 B
  float* logits = (float*)(ws + 263168);  // 8388608 B
  bf16* wgt = (bf16*)(ws + 8651776);      // 4194304 B
  float* part = (float*)(ws + 12846080);  // 4 x 2097152 B  (total ~20.3 MB)

  prep_kernel<<<dim3(Mn, Cn / 64), 256, 0, stream>>>(W, bias, av, Vhi, Vlo, c0);
  logits_kernel<<<dim3(Nn / 64, Bn), 256, 0, stream>>>(x, Vhi, Vlo, c0, logits);
  softmax_kernel<<<Bn * Mn, 256, 0, stream>>>(logits, wgt);
  pool_kernel<<<dim3(Cn / 64, Bn, 4), 256, 0, stream>>>(x, wgt, part);
  reduce_kernel<<<(Bn * Mn * Cn) / 1024, 256, 0, stream>>>(part, out);
}